// Round 4
// baseline (1948.940 us; speedup 1.0000x reference)
//
#include <hip/hip_runtime.h>
#include <type_traits>

typedef unsigned short u16;
typedef unsigned int   u32;
using short8 = __attribute__((ext_vector_type(8))) short;
using f32x4  = __attribute__((ext_vector_type(4))) float;

#define GLD_AS1 const __attribute__((address_space(1))) unsigned
#define GLD_AS3 __attribute__((address_space(3))) unsigned

static constexpr int NN = 8192;

// PROBE ROUND: every kernel takes a trailing `reps` arg and repeats its body
// (idempotent). Layer-1 instances are looped hard enough to surface in the
// rocprof top-5 (>165us/dispatch) with their counters. Baseline structure is
// otherwise byte-identical to the 572us round-1 kernel.

// ---------- bf16 helpers (manual RNE) ----------
__device__ __forceinline__ u16 f2bf(float f) {
  u32 u = __builtin_bit_cast(u32, f);
  u32 r = (u + 0x7FFFu + ((u >> 16) & 1u)) >> 16;
  return (u16)r;
}
__device__ __forceinline__ float bf2f(u16 h) {
  return __builtin_bit_cast(float, (u32)h << 16);
}
__device__ __forceinline__ short8 cvt8(f32x4 f0, f32x4 f1) {
  short8 r;
#pragma unroll
  for (int i = 0; i < 4; ++i) {
    r[i]     = (short)f2bf(f0[i]);
    r[4 + i] = (short)f2bf(f1[i]);
  }
  return r;
}

// ---------- kernel 1: fused rowsum + bf16 convert ----------
__global__ __launch_bounds__(256) void rowsum_cvt_k(const float* __restrict__ adj,
                                                    u16* __restrict__ adjb,
                                                    float* __restrict__ dinv,
                                                    int reps) {
  const int row = blockIdx.x;
  const f32x4* p = (const f32x4*)(adj + (size_t)row * NN);
  short8* w = (short8*)(adjb + (size_t)row * NN);
  __shared__ float partial[4];
  for (int rep = 0; rep < reps; ++rep) {
    asm volatile("" ::: "memory");  // defeat cross-rep load/store elimination
    float s = 0.f;
#pragma unroll
    for (int i = 0; i < 4; ++i) {
      const int idx = threadIdx.x + i * 256;  // pair index 0..1023
      f32x4 v0 = __builtin_nontemporal_load(p + 2 * idx);
      f32x4 v1 = __builtin_nontemporal_load(p + 2 * idx + 1);
      s += (v0[0] + v0[1]) + (v0[2] + v0[3]) + (v1[0] + v1[1]) + (v1[2] + v1[3]);
      w[idx] = cvt8(v0, v1);
    }
#pragma unroll
    for (int off = 32; off > 0; off >>= 1) s += __shfl_down(s, off, 64);
    if ((threadIdx.x & 63) == 0) partial[threadIdx.x >> 6] = s;
    __syncthreads();
    if (threadIdx.x == 0)
      dinv[row] = rsqrtf(partial[0] + partial[1] + partial[2] + partial[3] + 1.0f);
    __syncthreads();  // rep isolation (partial reuse)
  }
}

// ---------- kernel 2: u = dinv ∘ (X @ W);  Gt[c][r] = bf16(u), U[r][c] = bf16(u)
template <typename TIN>
__global__ __launch_bounds__(256) void featmul_k(const TIN* __restrict__ X,
                                                 const float* __restrict__ W,
                                                 const float* __restrict__ dinv,
                                                 u16* __restrict__ Gt,
                                                 u16* __restrict__ U,
                                                 int K, int C, int reps) {
  __shared__ __align__(16) u16 Wt[128][128];
  __shared__ float red[4][16][32];
  const int tid = threadIdx.x;
  for (int rep = 0; rep < reps; ++rep) {
    asm volatile("" ::: "memory");
    for (int idx = tid; idx < 128 * 128; idx += 256) {
      int c = idx & 127, k = idx >> 7;
      float w = (k < K && c < C) ? W[k * C + c] : 0.f;
      Wt[c][k] = f2bf(w);
    }
    __syncthreads();
    const int wv = tid >> 6, lane = tid & 63;
    const int q = lane >> 4, m16 = lane & 15;
    const int r0 = blockIdx.x * 16;
    const int c0 = wv * 32;
    f32x4 acc[2];
    acc[0] = {0.f, 0.f, 0.f, 0.f};
    acc[1] = {0.f, 0.f, 0.f, 0.f};
    const TIN* xrow = X + (size_t)(r0 + m16) * K;
    for (int k = 0; k < K; k += 32) {
      short8 af;
      if constexpr (std::is_same_v<TIN, float>) {
        f32x4 f0 = *(const f32x4*)(xrow + k + q * 8);
        f32x4 f1 = *(const f32x4*)(xrow + k + q * 8 + 4);
        af = cvt8(f0, f1);
      } else {
        af = __builtin_bit_cast(short8, *(const uint4*)(xrow + k + q * 8));
      }
#pragma unroll
      for (int nh = 0; nh < 2; ++nh) {
        short8 bf = *(const short8*)&Wt[c0 + nh * 16 + m16][k + q * 8];
        acc[nh] = __builtin_amdgcn_mfma_f32_16x16x32_bf16(af, bf, acc[nh], 0, 0, 0);
      }
    }
#pragma unroll
    for (int nh = 0; nh < 2; ++nh)
#pragma unroll
      for (int reg = 0; reg < 4; ++reg)
        red[wv][q * 4 + reg][nh * 16 + m16] = acc[nh][reg];
    __syncthreads();
    {
      const int cc = lane & 31, rh = lane >> 5;
      short8 t;
#pragma unroll
      for (int i = 0; i < 8; ++i) {
        int r = rh * 8 + i;
        t[i] = (short)f2bf(red[wv][r][cc] * dinv[r0 + r]);
        U[(size_t)(r0 + r) * 128 + c0 + cc] = (u16)t[i];
      }
      *(uint4*)(Gt + (size_t)(c0 + cc) * NN + r0 + rh * 8) = __builtin_bit_cast(uint4, t);
    }
    __syncthreads();  // rep isolation (Wt/red reuse)
  }
}

// ---------- kernel 3: partial GEMM (exact round-1 structure, 35us warm) ------
__global__ __launch_bounds__(512, 2) void gcn_gemm(const u16* __restrict__ Adjb,
                                                   const u16* __restrict__ Gt,
                                                   float* __restrict__ P,
                                                   int reps) {
  __shared__ __align__(16) u16 As[3][256 * 64];
  __shared__ __align__(16) u16 Bs[3][128 * 64];

  const int tid = threadIdx.x;
  const int wv = tid >> 6, lane = tid & 63;
  const int wm = wv >> 1, wn = wv & 1;
  const int q = lane >> 4, m16 = lane & 15;
  const int mbase = blockIdx.x * 256;
  const int kbase = blockIdx.y * 1024;
  float* Pt = P + (size_t)blockIdx.y * NN * 128;

  size_t aoff[4];
  int acl[4];
  size_t boff[2];
  int bcl[2];
#pragma unroll
  for (int i = 0; i < 4; ++i) {
    const int cl = i * 512 + tid;
    const int r = cl >> 3;
    const int g = (cl & 7) ^ (r & 7);
    aoff[i] = (size_t)(mbase + r) * NN + g * 8;
    acl[i] = cl;
  }
#pragma unroll
  for (int i = 0; i < 2; ++i) {
    const int cl = i * 512 + tid;
    const int r = cl >> 3;
    const int g = (cl & 7) ^ (r & 7);
    boff[i] = (size_t)r * NN + g * 8;
    bcl[i] = cl;
  }

  auto stage = [&](int buf, int kc) {
#pragma unroll
    for (int i = 0; i < 4; ++i)
      __builtin_amdgcn_global_load_lds((GLD_AS1*)(Adjb + aoff[i] + kc),
                                       (GLD_AS3*)(&As[buf][acl[i] * 8]), 16, 0, 0);
#pragma unroll
    for (int i = 0; i < 2; ++i)
      __builtin_amdgcn_global_load_lds((GLD_AS1*)(Gt + boff[i] + kc),
                                       (GLD_AS3*)(&Bs[buf][bcl[i] * 8]), 16, 0, 0);
  };

  f32x4 acc[4][4];
  for (int rep = 0; rep < reps; ++rep) {
#pragma unroll
    for (int a = 0; a < 4; ++a)
#pragma unroll
      for (int b = 0; b < 4; ++b) acc[a][b] = {0.f, 0.f, 0.f, 0.f};

    stage(0, kbase);
    stage(1, kbase + 64);
    for (int t = 0; t < 16; ++t) {
      const int buf = t % 3;
      if (t < 15) {
        asm volatile("s_waitcnt vmcnt(6)" ::: "memory");
      } else {
        asm volatile("s_waitcnt vmcnt(0)" ::: "memory");
      }
      __builtin_amdgcn_s_barrier();
      asm volatile("" ::: "memory");
      if (t + 2 < 16) stage((t + 2) % 3, kbase + (t + 2) * 64);
#pragma unroll
      for (int j = 0; j < 2; ++j) {
        short8 af[4], bf[4];
#pragma unroll
        for (int i = 0; i < 4; ++i) {
          const int m = wm * 64 + i * 16 + m16;
          const int n = wn * 64 + i * 16 + m16;
          af[i] = *(const short8*)&As[buf][m * 64 + (((j * 4 + q) ^ (m & 7)) << 3)];
          bf[i] = *(const short8*)&Bs[buf][n * 64 + (((j * 4 + q) ^ (n & 7)) << 3)];
        }
#pragma unroll
        for (int a = 0; a < 4; ++a)
#pragma unroll
          for (int b = 0; b < 4; ++b)
            acc[a][b] = __builtin_amdgcn_mfma_f32_16x16x32_bf16(af[a], bf[b], acc[a][b], 0, 0, 0);
      }
    }
    __syncthreads();  // rep isolation (As[0] reused by next rep's stage)
  }

#pragma unroll
  for (int a = 0; a < 4; ++a) {
#pragma unroll
    for (int b = 0; b < 4; ++b) {
      const int c = wn * 64 + b * 16 + m16;
#pragma unroll
      for (int reg = 0; reg < 4; ++reg) {
        const int r = mbase + wm * 64 + a * 16 + q * 4 + reg;
        Pt[(size_t)r * 128 + c] = acc[a][b][reg];
      }
    }
  }
}

// ---------- kernel 4: finalize ----------
template <int RELU, int OUT_F32>
__global__ __launch_bounds__(256) void finalize_k(const float* __restrict__ P,
                                                  const u16* __restrict__ U,
                                                  const float* __restrict__ dinv,
                                                  const float* __restrict__ bias,
                                                  u16* __restrict__ Hout,
                                                  float* __restrict__ Fout,
                                                  int reps) {
  const int tid = threadIdx.x;
  const int c = tid & 127;
  const int r = blockIdx.x * 2 + (tid >> 7);
  const size_t idx = (size_t)r * 128 + c;
  for (int rep = 0; rep < reps; ++rep) {
    asm volatile("" ::: "memory");
    float s = 0.f;
#pragma unroll
    for (int k = 0; k < 8; ++k) s += P[(size_t)k * NN * 128 + idx];
    s += bf2f(U[idx]);
    s = dinv[r] * s + bias[c];
    if (RELU) s = fmaxf(s, 0.f);
    if (OUT_F32) {
      if (c < 64) Fout[(size_t)r * 64 + c] = s;
    } else {
      Hout[idx] = f2bf(s);
    }
  }
}

// ---------- launch ----------
extern "C" void kernel_launch(void* const* d_in, const int* in_sizes, int n_in,
                              void* d_out, int out_size, void* d_ws, size_t ws_size,
                              hipStream_t stream) {
  const float* x   = (const float*)d_in[0];
  const float* adj = (const float*)d_in[1];
  const float* W0  = (const float*)d_in[2];
  const float* b0  = (const float*)d_in[3];
  const float* W1  = (const float*)d_in[4];
  const float* b1  = (const float*)d_in[5];
  const float* W2  = (const float*)d_in[6];
  const float* b2  = (const float*)d_in[7];
  float* out = (float*)d_out;

  char* ws = (char*)d_ws;
  float* dinv = (float*)ws;                      // 32 KB   @ 0
  u16* Gt     = (u16*)(ws + (1u << 20));         // 2 MB    @ 1 MB   [128][8192]
  u16* U      = (u16*)(ws + (4u << 20));         // 2 MB    @ 4 MB   [8192][128]
  u16* h      = (u16*)(ws + (6u << 20));         // 2 MB    @ 6 MB   [8192][128]
  float* Pp   = (float*)(ws + (8u << 20));       // 32 MB   @ 8 MB   [8][8192][128]
  u16* adjb   = (u16*)(ws + (48u << 20));        // 134 MB  @ 48 MB  [8192][8192]

  const dim3 ggrid(32, 8);

  // PROBES: rowsum x8; layer-1 featmul x48, gemm x8, finalize x48.
  rowsum_cvt_k<<<NN, 256, 0, stream>>>(adj, adjb, dinv, 8);

  // layer 0 (reps=1 everywhere)
  featmul_k<float><<<NN / 16, 256, 0, stream>>>(x, W0, dinv, Gt, U, 64, 128, 1);
  gcn_gemm<<<ggrid, 512, 0, stream>>>(adjb, Gt, Pp, 1);
  finalize_k<1, 0><<<NN / 2, 256, 0, stream>>>(Pp, U, dinv, b0, h, nullptr, 1);

  // layer 1 (probed)
  featmul_k<u16><<<NN / 16, 256, 0, stream>>>(h, W1, dinv, Gt, U, 128, 128, 48);
  gcn_gemm<<<ggrid, 512, 0, stream>>>(adjb, Gt, Pp, 8);
  finalize_k<1, 0><<<NN / 2, 256, 0, stream>>>(Pp, U, dinv, b1, h, nullptr, 48);

  // layer 2 (reps=1)
  featmul_k<u16><<<NN / 16, 256, 0, stream>>>(h, W2, dinv, Gt, U, 128, 64, 1);
  gcn_gemm<<<ggrid, 512, 0, stream>>>(adjb, Gt, Pp, 1);
  finalize_k<0, 1><<<NN / 2, 256, 0, stream>>>(Pp, U, dinv, b2, nullptr, out, 1);
}

// Round 5
// 566.516 us; speedup vs baseline: 3.4402x; 3.4402x over previous
//
#include <hip/hip_runtime.h>
#include <type_traits>

typedef unsigned short u16;
typedef unsigned int   u32;
using short8 = __attribute__((ext_vector_type(8))) short;
using f32x4  = __attribute__((ext_vector_type(4))) float;

#define GLD_AS1 const __attribute__((address_space(1))) unsigned
#define GLD_AS3 __attribute__((address_space(3))) unsigned

static constexpr int NN = 8192;

// ---------- bf16 helpers (manual RNE) ----------
__device__ __forceinline__ u16 f2bf(float f) {
  u32 u = __builtin_bit_cast(u32, f);
  u32 r = (u + 0x7FFFu + ((u >> 16) & 1u)) >> 16;
  return (u16)r;
}
__device__ __forceinline__ float bf2f(u16 h) {
  return __builtin_bit_cast(float, (u32)h << 16);
}
__device__ __forceinline__ short8 cvt8(f32x4 f0, f32x4 f1) {
  short8 r;
#pragma unroll
  for (int i = 0; i < 4; ++i) {
    r[i]     = (short)f2bf(f0[i]);
    r[4 + i] = (short)f2bf(f1[i]);
  }
  return r;
}

// ---------- kernel 1: fused rowsum + bf16 convert (16B stores) ----------
// adj read once (nontemporal: don't evict adjb from LLC); adjb re-read 3x.
__global__ __launch_bounds__(256) void rowsum_cvt_k(const float* __restrict__ adj,
                                                    u16* __restrict__ adjb,
                                                    float* __restrict__ dinv) {
  const int row = blockIdx.x;
  const f32x4* p = (const f32x4*)(adj + (size_t)row * NN);
  short8* w = (short8*)(adjb + (size_t)row * NN);
  float s = 0.f;
#pragma unroll
  for (int i = 0; i < 4; ++i) {
    const int idx = threadIdx.x + i * 256;  // pair index 0..1023
    f32x4 v0 = __builtin_nontemporal_load(p + 2 * idx);
    f32x4 v1 = __builtin_nontemporal_load(p + 2 * idx + 1);
    s += (v0[0] + v0[1]) + (v0[2] + v0[3]) + (v1[0] + v1[1]) + (v1[2] + v1[3]);
    w[idx] = cvt8(v0, v1);
  }
#pragma unroll
  for (int off = 32; off > 0; off >>= 1) s += __shfl_down(s, off, 64);
  __shared__ float partial[4];
  if ((threadIdx.x & 63) == 0) partial[threadIdx.x >> 6] = s;
  __syncthreads();
  if (threadIdx.x == 0)
    dinv[row] = rsqrtf(partial[0] + partial[1] + partial[2] + partial[3] + 1.0f);
}

// ---------- kernel 2: u = dinv ∘ (X @ W);  Gt[c][r] = bf16(u), U[r][c] = bf16(u)
// BANK-CONFLICT FIX (round-4 counters: 8.6M conflicts/dispatch, 16.2us each):
// Wt rows were 256 B (stride = 0 mod 32 banks) -> 16-way frag-read conflicts +
// 64-way staging-write conflicts. Row stride now 152 u16 = 304 B (16B-aligned
// for ds_read_b128; bank step 12 mod 32 -> m16 lanes spread over 8 banks, 2-way
// = free; staging writes 8-way). red padded [32]->[36] (4-way -> 2-way free).
template <typename TIN>
__global__ __launch_bounds__(256) void featmul_k(const TIN* __restrict__ X,
                                                 const float* __restrict__ W,
                                                 const float* __restrict__ dinv,
                                                 u16* __restrict__ Gt,
                                                 u16* __restrict__ U,
                                                 int K, int C) {
  __shared__ __align__(16) u16 Wt[128][152];
  __shared__ float red[4][16][36];
  const int tid = threadIdx.x;
  for (int idx = tid; idx < 128 * 128; idx += 256) {
    int c = idx & 127, k = idx >> 7;
    float w = (k < K && c < C) ? W[k * C + c] : 0.f;
    Wt[c][k] = f2bf(w);
  }
  __syncthreads();
  const int wv = tid >> 6, lane = tid & 63;
  const int q = lane >> 4, m16 = lane & 15;
  const int r0 = blockIdx.x * 16;
  const int c0 = wv * 32;
  f32x4 acc[2];
  acc[0] = {0.f, 0.f, 0.f, 0.f};
  acc[1] = {0.f, 0.f, 0.f, 0.f};
  const TIN* xrow = X + (size_t)(r0 + m16) * K;
  for (int k = 0; k < K; k += 32) {
    short8 af;
    if constexpr (std::is_same_v<TIN, float>) {
      f32x4 f0 = *(const f32x4*)(xrow + k + q * 8);
      f32x4 f1 = *(const f32x4*)(xrow + k + q * 8 + 4);
      af = cvt8(f0, f1);
    } else {
      af = __builtin_bit_cast(short8, *(const uint4*)(xrow + k + q * 8));
    }
#pragma unroll
    for (int nh = 0; nh < 2; ++nh) {
      short8 bf = *(const short8*)&Wt[c0 + nh * 16 + m16][k + q * 8];
      acc[nh] = __builtin_amdgcn_mfma_f32_16x16x32_bf16(af, bf, acc[nh], 0, 0, 0);
    }
  }
#pragma unroll
  for (int nh = 0; nh < 2; ++nh)
#pragma unroll
    for (int reg = 0; reg < 4; ++reg)
      red[wv][q * 4 + reg][nh * 16 + m16] = acc[nh][reg];
  __syncthreads();
  {
    const int cc = lane & 31, rh = lane >> 5;
    short8 t;
#pragma unroll
    for (int i = 0; i < 8; ++i) {
      int r = rh * 8 + i;
      t[i] = (short)f2bf(red[wv][r][cc] * dinv[r0 + r]);
      U[(size_t)(r0 + r) * 128 + c0 + cc] = (u16)t[i];
    }
    *(uint4*)(Gt + (size_t)(c0 + cc) * NN + r0 + rh * 8) = __builtin_bit_cast(uint4, t);
  }
}

// ---------- kernel 3: partial GEMM  P[ks] = adjb[mtile, krange] @ Gt^T[krange, :]
// Round-1 structure (measured ~33-35us warm). 256x128 tile, BK=64, 512 thr,
// 3-stage pipeline, counted vmcnt(6), global_load_lds(16), xor swizzle.
// grid (32 mtiles, 8 ksplits) = 256 blocks = 1/CU (144 KB LDS).
__global__ __launch_bounds__(512, 2) void gcn_gemm(const u16* __restrict__ Adjb,
                                                   const u16* __restrict__ Gt,
                                                   float* __restrict__ P) {
  __shared__ __align__(16) u16 As[3][256 * 64];  // 32 KB per buf
  __shared__ __align__(16) u16 Bs[3][128 * 64];  // 16 KB per buf

  const int tid = threadIdx.x;
  const int wv = tid >> 6, lane = tid & 63;
  const int wm = wv >> 1, wn = wv & 1;
  const int q = lane >> 4, m16 = lane & 15;
  const int mbase = blockIdx.x * 256;
  const int kbase = blockIdx.y * 1024;
  float* Pt = P + (size_t)blockIdx.y * NN * 128;

  size_t aoff[4];
  int acl[4];
  size_t boff[2];
  int bcl[2];
#pragma unroll
  for (int i = 0; i < 4; ++i) {
    const int cl = i * 512 + tid;       // A chunk-linear 0..2047
    const int r = cl >> 3;              // row 0..255 (8 chunks/row)
    const int g = (cl & 7) ^ (r & 7);   // xor-swizzled global chunk
    aoff[i] = (size_t)(mbase + r) * NN + g * 8;
    acl[i] = cl;
  }
#pragma unroll
  for (int i = 0; i < 2; ++i) {
    const int cl = i * 512 + tid;       // B chunk-linear 0..1023
    const int r = cl >> 3;              // row 0..127
    const int g = (cl & 7) ^ (r & 7);
    boff[i] = (size_t)r * NN + g * 8;
    bcl[i] = cl;
  }

  auto stage = [&](int buf, int kc) {   // 6 loads/thread => vmcnt +6
#pragma unroll
    for (int i = 0; i < 4; ++i)
      __builtin_amdgcn_global_load_lds((GLD_AS1*)(Adjb + aoff[i] + kc),
                                       (GLD_AS3*)(&As[buf][acl[i] * 8]), 16, 0, 0);
#pragma unroll
    for (int i = 0; i < 2; ++i)
      __builtin_amdgcn_global_load_lds((GLD_AS1*)(Gt + boff[i] + kc),
                                       (GLD_AS3*)(&Bs[buf][bcl[i] * 8]), 16, 0, 0);
  };

  f32x4 acc[4][4];
#pragma unroll
  for (int a = 0; a < 4; ++a)
#pragma unroll
    for (int b = 0; b < 4; ++b) acc[a][b] = {0.f, 0.f, 0.f, 0.f};

  stage(0, kbase);
  stage(1, kbase + 64);
  for (int t = 0; t < 16; ++t) {
    const int buf = t % 3;
    if (t < 15) {
      asm volatile("s_waitcnt vmcnt(6)" ::: "memory");
    } else {
      asm volatile("s_waitcnt vmcnt(0)" ::: "memory");
    }
    __builtin_amdgcn_s_barrier();
    asm volatile("" ::: "memory");
    if (t + 2 < 16) stage((t + 2) % 3, kbase + (t + 2) * 64);
#pragma unroll
    for (int j = 0; j < 2; ++j) {
      short8 af[4], bf[4];
#pragma unroll
      for (int i = 0; i < 4; ++i) {
        const int m = wm * 64 + i * 16 + m16;
        const int n = wn * 64 + i * 16 + m16;
        af[i] = *(const short8*)&As[buf][m * 64 + (((j * 4 + q) ^ (m & 7)) << 3)];
        bf[i] = *(const short8*)&Bs[buf][n * 64 + (((j * 4 + q) ^ (n & 7)) << 3)];
      }
#pragma unroll
      for (int a = 0; a < 4; ++a)
#pragma unroll
        for (int b = 0; b < 4; ++b)
          acc[a][b] = __builtin_amdgcn_mfma_f32_16x16x32_bf16(af[a], bf[b], acc[a][b], 0, 0, 0);
    }
  }

#pragma unroll
  for (int a = 0; a < 4; ++a) {
#pragma unroll
    for (int b = 0; b < 4; ++b) {
      const int c = wn * 64 + b * 16 + m16;
#pragma unroll
      for (int reg = 0; reg < 4; ++reg) {
        const int r = mbase + wm * 64 + a * 16 + q * 4 + reg;
        Pt[(size_t)r * 128 + c] = acc[a][b][reg];
      }
    }
  }
}

// ---------- kernel 4: finalize  out = ep( dinv[r]*(sum_s P[s] + u) + bias ) ----
template <int RELU, int OUT_F32>
__global__ __launch_bounds__(256) void finalize_k(const float* __restrict__ P,
                                                  const u16* __restrict__ U,
                                                  const float* __restrict__ dinv,
                                                  const float* __restrict__ bias,
                                                  u16* __restrict__ Hout,
                                                  float* __restrict__ Fout) {
  const int tid = threadIdx.x;
  const int c = tid & 127;
  const int r = blockIdx.x * 2 + (tid >> 7);
  const size_t idx = (size_t)r * 128 + c;
  float s = 0.f;
#pragma unroll
  for (int k = 0; k < 8; ++k) s += P[(size_t)k * NN * 128 + idx];
  s += bf2f(U[idx]);
  s = dinv[r] * s + bias[c];
  if (RELU) s = fmaxf(s, 0.f);
  if (OUT_F32) {
    if (c < 64) Fout[(size_t)r * 64 + c] = s;
  } else {
    Hout[idx] = f2bf(s);
  }
}

// ---------- launch ----------
extern "C" void kernel_launch(void* const* d_in, const int* in_sizes, int n_in,
                              void* d_out, int out_size, void* d_ws, size_t ws_size,
                              hipStream_t stream) {
  const float* x   = (const float*)d_in[0];  // [8192][64]
  const float* adj = (const float*)d_in[1];  // [8192][8192]
  const float* W0  = (const float*)d_in[2];  // [64][128]
  const float* b0  = (const float*)d_in[3];  // [128]
  const float* W1  = (const float*)d_in[4];  // [128][128]
  const float* b1  = (const float*)d_in[5];  // [128]
  const float* W2  = (const float*)d_in[6];  // [128][64]
  const float* b2  = (const float*)d_in[7];  // [64]
  float* out = (float*)d_out;                // [8192][64] fp32

  char* ws = (char*)d_ws;
  float* dinv = (float*)ws;                      // 32 KB   @ 0
  u16* Gt     = (u16*)(ws + (1u << 20));         // 2 MB    @ 1 MB   [128][8192]
  u16* U      = (u16*)(ws + (4u << 20));         // 2 MB    @ 4 MB   [8192][128]
  u16* h      = (u16*)(ws + (6u << 20));         // 2 MB    @ 6 MB   [8192][128]
  float* Pp   = (float*)(ws + (8u << 20));       // 32 MB   @ 8 MB   [8][8192][128] fp32
  u16* adjb   = (u16*)(ws + (48u << 20));        // 134 MB  @ 48 MB  [8192][8192]

  const dim3 ggrid(32, 8);

  rowsum_cvt_k<<<NN, 256, 0, stream>>>(adj, adjb, dinv);

  // layer 0
  featmul_k<float><<<NN / 16, 256, 0, stream>>>(x, W0, dinv, Gt, U, 64, 128);
  gcn_gemm<<<ggrid, 512, 0, stream>>>(adjb, Gt, Pp);
  finalize_k<1, 0><<<NN / 2, 256, 0, stream>>>(Pp, U, dinv, b0, h, nullptr);

  // layer 1
  featmul_k<u16><<<NN / 16, 256, 0, stream>>>(h, W1, dinv, Gt, U, 128, 128);
  gcn_gemm<<<ggrid, 512, 0, stream>>>(adjb, Gt, Pp);
  finalize_k<1, 0><<<NN / 2, 256, 0, stream>>>(Pp, U, dinv, b1, h, nullptr);

  // layer 2 (identity act, fp32 out, cols 64..127 of Gt/U are zero)
  featmul_k<u16><<<NN / 16, 256, 0, stream>>>(h, W2, dinv, Gt, U, 128, 64);
  gcn_gemm<<<ggrid, 512, 0, stream>>>(adjb, Gt, Pp);
  finalize_k<0, 1><<<NN / 2, 256, 0, stream>>>(Pp, U, dinv, b2, nullptr, out);
}

// Round 6
// 515.161 us; speedup vs baseline: 3.7832x; 1.0997x over previous
//
#include <hip/hip_runtime.h>
#include <type_traits>

typedef unsigned short u16;
typedef unsigned int   u32;
using short8 = __attribute__((ext_vector_type(8))) short;
using f32x4  = __attribute__((ext_vector_type(4))) float;

#define GLD_AS1 const __attribute__((address_space(1))) unsigned
#define GLD_AS3 __attribute__((address_space(3))) unsigned

static constexpr int NN = 8192;

// ---------- bf16 helpers (manual RNE) ----------
__device__ __forceinline__ u16 f2bf(float f) {
  u32 u = __builtin_bit_cast(u32, f);
  u32 r = (u + 0x7FFFu + ((u >> 16) & 1u)) >> 16;
  return (u16)r;
}
__device__ __forceinline__ float bf2f(u16 h) {
  return __builtin_bit_cast(float, (u32)h << 16);
}
__device__ __forceinline__ short8 cvt8(f32x4 f0, f32x4 f1) {
  short8 r;
#pragma unroll
  for (int i = 0; i < 4; ++i) {
    r[i]     = (short)f2bf(f0[i]);
    r[4 + i] = (short)f2bf(f1[i]);
  }
  return r;
}

// ---------- kernel 1: fused rowsum + bf16 convert (16B stores) ----------
__global__ __launch_bounds__(256) void rowsum_cvt_k(const float* __restrict__ adj,
                                                    u16* __restrict__ adjb,
                                                    float* __restrict__ dinv) {
  const int row = blockIdx.x;
  const f32x4* p = (const f32x4*)(adj + (size_t)row * NN);
  short8* w = (short8*)(adjb + (size_t)row * NN);
  float s = 0.f;
#pragma unroll
  for (int i = 0; i < 4; ++i) {
    const int idx = threadIdx.x + i * 256;  // pair index 0..1023
    f32x4 v0 = __builtin_nontemporal_load(p + 2 * idx);
    f32x4 v1 = __builtin_nontemporal_load(p + 2 * idx + 1);
    s += (v0[0] + v0[1]) + (v0[2] + v0[3]) + (v1[0] + v1[1]) + (v1[2] + v1[3]);
    w[idx] = cvt8(v0, v1);
  }
#pragma unroll
  for (int off = 32; off > 0; off >>= 1) s += __shfl_down(s, off, 64);
  __shared__ float partial[4];
  if ((threadIdx.x & 63) == 0) partial[threadIdx.x >> 6] = s;
  __syncthreads();
  if (threadIdx.x == 0)
    dinv[row] = rsqrtf(partial[0] + partial[1] + partial[2] + partial[3] + 1.0f);
}

// ---------- kernel 2: u = dinv ∘ (X @ W);  Gt[c][r] = bf16(u), U[r][c] = bf16(u)
// LATENCY FIX (round-5 analysis: 38K cyc/block, ~85% issue-idle; old staging
// loop serialized 64 dependent L2 loads ~19K cyc):
//  - W staging: (c,kh) mapping, 4 batches x 16 independent coalesced loads ->
//    regs -> LDS (4 latency waves instead of 64).
//  - X fragments prefetched before the MFMA loop (all issued together).
//  - dinv prefetched at kernel start.
// Wt padded rows (152 u16 = 304 B) keep frag reads conflict-free; staging
// writes 8-way (was 64-way at 256 B stride).
template <typename TIN>
__global__ __launch_bounds__(256) void featmul_k(const TIN* __restrict__ X,
                                                 const float* __restrict__ W,
                                                 const float* __restrict__ dinv,
                                                 u16* __restrict__ Gt,
                                                 u16* __restrict__ U,
                                                 int K, int C) {
  __shared__ __align__(16) u16 Wt[128][152];
  __shared__ float red[4][16][36];
  const int tid = threadIdx.x;
  const int wv = tid >> 6, lane = tid & 63;
  const int q = lane >> 4, m16 = lane & 15;
  const int r0 = blockIdx.x * 16;
  const int c0 = wv * 32;

  // dinv prefetch (independent; hides under W staging)
  const int rh0 = lane >> 5;  // used in epilogue; prefetch all 16 rows' dinv
  float dv[8];
#pragma unroll
  for (int i = 0; i < 8; ++i) dv[i] = dinv[r0 + rh0 * 8 + i];

  // X prefetch: all af fragments issued before use
  const int nk = K >> 5;  // 2 (K=64) or 4 (K=128)
  const TIN* xrow = X + (size_t)(r0 + m16) * K;
  short8 afr[4];
  if constexpr (std::is_same_v<TIN, float>) {
    f32x4 xf[8];
#pragma unroll
    for (int kk = 0; kk < 4; ++kk) {
      if (kk < nk) {
        xf[2 * kk]     = *(const f32x4*)(xrow + kk * 32 + q * 8);
        xf[2 * kk + 1] = *(const f32x4*)(xrow + kk * 32 + q * 8 + 4);
      }
    }
#pragma unroll
    for (int kk = 0; kk < 4; ++kk)
      if (kk < nk) afr[kk] = cvt8(xf[2 * kk], xf[2 * kk + 1]);
  } else {
#pragma unroll
    for (int kk = 0; kk < 4; ++kk)
      if (kk < nk) afr[kk] = __builtin_bit_cast(short8, *(const uint4*)(xrow + kk * 32 + q * 8));
  }

  // W staging: c = tid&127 (coalesced across lanes), kh = tid>>7 selects k-half.
  {
    const int c = tid & 127;
    const int kh = tid >> 7;  // 0,1
#pragma unroll
    for (int b = 0; b < 4; ++b) {
      float wreg[16];
#pragma unroll
      for (int i = 0; i < 16; ++i) {
        const int k = kh * 64 + b * 16 + i;
        wreg[i] = (k < K && c < C) ? W[k * C + c] : 0.f;
      }
#pragma unroll
      for (int i = 0; i < 16; ++i) Wt[c][kh * 64 + b * 16 + i] = f2bf(wreg[i]);
    }
  }
  __syncthreads();

  f32x4 acc[2];
  acc[0] = {0.f, 0.f, 0.f, 0.f};
  acc[1] = {0.f, 0.f, 0.f, 0.f};
#pragma unroll
  for (int kk = 0; kk < 4; ++kk) {
    if (kk < nk) {
#pragma unroll
      for (int nh = 0; nh < 2; ++nh) {
        short8 bf = *(const short8*)&Wt[c0 + nh * 16 + m16][kk * 32 + q * 8];
        acc[nh] = __builtin_amdgcn_mfma_f32_16x16x32_bf16(afr[kk], bf, acc[nh], 0, 0, 0);
      }
    }
  }
#pragma unroll
  for (int nh = 0; nh < 2; ++nh)
#pragma unroll
    for (int reg = 0; reg < 4; ++reg)
      red[wv][q * 4 + reg][nh * 16 + m16] = acc[nh][reg];
  __syncthreads();
  {
    const int cc = lane & 31, rh = lane >> 5;
    short8 t;
#pragma unroll
    for (int i = 0; i < 8; ++i) {
      int r = rh * 8 + i;
      t[i] = (short)f2bf(red[wv][r][cc] * dv[i]);
      U[(size_t)(r0 + r) * 128 + c0 + cc] = (u16)t[i];
    }
    *(uint4*)(Gt + (size_t)(c0 + cc) * NN + r0 + rh * 8) = __builtin_bit_cast(uint4, t);
  }
}

// ---------- kernel 3: partial GEMM  P[ks] = adjb[mtile, krange] @ Gt^T[krange, :]
// Round-1 structure (measured ~33-35us warm). 256x128 tile, BK=64, 512 thr,
// 3-stage pipeline, counted vmcnt(6), global_load_lds(16), xor swizzle.
// grid (32 mtiles, 8 ksplits) = 256 blocks = 1/CU (144 KB LDS).
__global__ __launch_bounds__(512, 2) void gcn_gemm(const u16* __restrict__ Adjb,
                                                   const u16* __restrict__ Gt,
                                                   float* __restrict__ P) {
  __shared__ __align__(16) u16 As[3][256 * 64];  // 32 KB per buf
  __shared__ __align__(16) u16 Bs[3][128 * 64];  // 16 KB per buf

  const int tid = threadIdx.x;
  const int wv = tid >> 6, lane = tid & 63;
  const int wm = wv >> 1, wn = wv & 1;
  const int q = lane >> 4, m16 = lane & 15;
  const int mbase = blockIdx.x * 256;
  const int kbase = blockIdx.y * 1024;
  float* Pt = P + (size_t)blockIdx.y * NN * 128;

  size_t aoff[4];
  int acl[4];
  size_t boff[2];
  int bcl[2];
#pragma unroll
  for (int i = 0; i < 4; ++i) {
    const int cl = i * 512 + tid;       // A chunk-linear 0..2047
    const int r = cl >> 3;              // row 0..255 (8 chunks/row)
    const int g = (cl & 7) ^ (r & 7);   // xor-swizzled global chunk
    aoff[i] = (size_t)(mbase + r) * NN + g * 8;
    acl[i] = cl;
  }
#pragma unroll
  for (int i = 0; i < 2; ++i) {
    const int cl = i * 512 + tid;       // B chunk-linear 0..1023
    const int r = cl >> 3;              // row 0..127
    const int g = (cl & 7) ^ (r & 7);
    boff[i] = (size_t)r * NN + g * 8;
    bcl[i] = cl;
  }

  auto stage = [&](int buf, int kc) {   // 6 loads/thread => vmcnt +6
#pragma unroll
    for (int i = 0; i < 4; ++i)
      __builtin_amdgcn_global_load_lds((GLD_AS1*)(Adjb + aoff[i] + kc),
                                       (GLD_AS3*)(&As[buf][acl[i] * 8]), 16, 0, 0);
#pragma unroll
    for (int i = 0; i < 2; ++i)
      __builtin_amdgcn_global_load_lds((GLD_AS1*)(Gt + boff[i] + kc),
                                       (GLD_AS3*)(&Bs[buf][bcl[i] * 8]), 16, 0, 0);
  };

  f32x4 acc[4][4];
#pragma unroll
  for (int a = 0; a < 4; ++a)
#pragma unroll
    for (int b = 0; b < 4; ++b) acc[a][b] = {0.f, 0.f, 0.f, 0.f};

  stage(0, kbase);
  stage(1, kbase + 64);
  for (int t = 0; t < 16; ++t) {
    const int buf = t % 3;
    if (t < 15) {
      asm volatile("s_waitcnt vmcnt(6)" ::: "memory");
    } else {
      asm volatile("s_waitcnt vmcnt(0)" ::: "memory");
    }
    __builtin_amdgcn_s_barrier();
    asm volatile("" ::: "memory");
    if (t + 2 < 16) stage((t + 2) % 3, kbase + (t + 2) * 64);
#pragma unroll
    for (int j = 0; j < 2; ++j) {
      short8 af[4], bf[4];
#pragma unroll
      for (int i = 0; i < 4; ++i) {
        const int m = wm * 64 + i * 16 + m16;
        const int n = wn * 64 + i * 16 + m16;
        af[i] = *(const short8*)&As[buf][m * 64 + (((j * 4 + q) ^ (m & 7)) << 3)];
        bf[i] = *(const short8*)&Bs[buf][n * 64 + (((j * 4 + q) ^ (n & 7)) << 3)];
      }
#pragma unroll
      for (int a = 0; a < 4; ++a)
#pragma unroll
        for (int b = 0; b < 4; ++b)
          acc[a][b] = __builtin_amdgcn_mfma_f32_16x16x32_bf16(af[a], bf[b], acc[a][b], 0, 0, 0);
    }
  }

#pragma unroll
  for (int a = 0; a < 4; ++a) {
#pragma unroll
    for (int b = 0; b < 4; ++b) {
      const int c = wn * 64 + b * 16 + m16;
#pragma unroll
      for (int reg = 0; reg < 4; ++reg) {
        const int r = mbase + wm * 64 + a * 16 + q * 4 + reg;
        Pt[(size_t)r * 128 + c] = acc[a][b][reg];
      }
    }
  }
}

// ---------- kernel 4: finalize  out = ep( dinv[r]*(sum_s P[s] + u) + bias ) ----
template <int RELU, int OUT_F32>
__global__ __launch_bounds__(256) void finalize_k(const float* __restrict__ P,
                                                  const u16* __restrict__ U,
                                                  const float* __restrict__ dinv,
                                                  const float* __restrict__ bias,
                                                  u16* __restrict__ Hout,
                                                  float* __restrict__ Fout) {
  const int tid = threadIdx.x;
  const int c = tid & 127;
  const int r = blockIdx.x * 2 + (tid >> 7);
  const size_t idx = (size_t)r * 128 + c;
  float s = 0.f;
#pragma unroll
  for (int k = 0; k < 8; ++k) s += P[(size_t)k * NN * 128 + idx];
  s += bf2f(U[idx]);
  s = dinv[r] * s + bias[c];
  if (RELU) s = fmaxf(s, 0.f);
  if (OUT_F32) {
    if (c < 64) Fout[(size_t)r * 64 + c] = s;
  } else {
    Hout[idx] = f2bf(s);
  }
}

// ---------- launch ----------
extern "C" void kernel_launch(void* const* d_in, const int* in_sizes, int n_in,
                              void* d_out, int out_size, void* d_ws, size_t ws_size,
                              hipStream_t stream) {
  const float* x   = (const float*)d_in[0];  // [8192][64]
  const float* adj = (const float*)d_in[1];  // [8192][8192]
  const float* W0  = (const float*)d_in[2];  // [64][128]
  const float* b0  = (const float*)d_in[3];  // [128]
  const float* W1  = (const float*)d_in[4];  // [128][128]
  const float* b1  = (const float*)d_in[5];  // [128]
  const float* W2  = (const float*)d_in[6];  // [128][64]
  const float* b2  = (const float*)d_in[7];  // [64]
  float* out = (float*)d_out;                // [8192][64] fp32

  char* ws = (char*)d_ws;
  float* dinv = (float*)ws;                      // 32 KB   @ 0
  u16* Gt     = (u16*)(ws + (1u << 20));         // 2 MB    @ 1 MB   [128][8192]
  u16* U      = (u16*)(ws + (4u << 20));         // 2 MB    @ 4 MB   [8192][128]
  u16* h      = (u16*)(ws + (6u << 20));         // 2 MB    @ 6 MB   [8192][128]
  float* Pp   = (float*)(ws + (8u << 20));       // 32 MB   @ 8 MB   [8][8192][128] fp32
  u16* adjb   = (u16*)(ws + (48u << 20));        // 134 MB  @ 48 MB  [8192][8192]

  const dim3 ggrid(32, 8);

  rowsum_cvt_k<<<NN, 256, 0, stream>>>(adj, adjb, dinv);

  // layer 0
  featmul_k<float><<<NN / 16, 256, 0, stream>>>(x, W0, dinv, Gt, U, 64, 128);
  gcn_gemm<<<ggrid, 512, 0, stream>>>(adjb, Gt, Pp);
  finalize_k<1, 0><<<NN / 2, 256, 0, stream>>>(Pp, U, dinv, b0, h, nullptr);

  // layer 1
  featmul_k<u16><<<NN / 16, 256, 0, stream>>>(h, W1, dinv, Gt, U, 128, 128);
  gcn_gemm<<<ggrid, 512, 0, stream>>>(adjb, Gt, Pp);
  finalize_k<1, 0><<<NN / 2, 256, 0, stream>>>(Pp, U, dinv, b1, h, nullptr);

  // layer 2 (identity act, fp32 out, cols 64..127 of Gt/U are zero)
  featmul_k<u16><<<NN / 16, 256, 0, stream>>>(h, W2, dinv, Gt, U, 128, 64);
  gcn_gemm<<<ggrid, 512, 0, stream>>>(adjb, Gt, Pp);
  finalize_k<0, 1><<<NN / 2, 256, 0, stream>>>(Pp, U, dinv, b2, nullptr, out);
}